// Round 5
// baseline (146.728 us; speedup 1.0000x reference)
//
#include <hip/hip_runtime.h>
#include <stdint.h>

#define NFREQ 256
#define NB 16
#define NT 4096
#define LOUT 1048832          // (4096+1)*256
#define TROWS 129             // t = j0-1 .. j0+127
#define TROWSZ 132            // u32 per T row: 128 payload + 4 pad (528 B)

typedef __bf16 bf16;
typedef __bf16 bf16x8 __attribute__((ext_vector_type(8)));
typedef float floatx4 __attribute__((ext_vector_type(4)));

__device__ inline uint32_t f_as_u(float x) { union { float f; uint32_t u; } v; v.f = x; return v.u; }

// kbF frag-major: kbF[k'/32][n][k'%32] = Kb[n][k'],
//   Kb[n][f'] = (f'<256 ? K[n+256][f'] : K[n][f'-256]) / 128  (bf16 RNE)
__global__ __launch_bounds__(256) void build_kb(const float* __restrict__ ker,
                                                bf16* __restrict__ kbF) {
    int idx = blockIdx.x * 256 + threadIdx.x;   // 131072 total
    int n = idx >> 9, f = idx & 511;
    float v = (f < 256) ? ker[(n + 256) * 256 + f] : ker[n * 256 + (f - 256)];
    uint32_t u = f_as_u(v * 0.0078125f);
    uint32_t rr = (u + 0x7fffu + ((u >> 16) & 1u)) >> 16;
    union { uint16_t u; bf16 b; } o; o.u = (uint16_t)rr;
    kbF[((size_t)(f >> 5) * 256 + n) * 32 + (f & 31)] = o.b;
}

// out[b][j*256+n] = sum_{f'<512} Avirt[j][f'] * Kb[n][f'],
//   Avirt[j][f'] = spec[b][f'&255][j-1+(f'>=256)]   (0 outside t-range)
// Block: 128 j x 256 n. LDS T[129][256]bf16 staged once (ONE barrier).
// K-loop kchunk-outer: 4 B-frag global loads (L2-hot kbF) feed 32 MFMAs.
__global__ __launch_bounds__(256, 2) void imdct_gemm(const float* __restrict__ spec,
                                                     const bf16* __restrict__ kbF,
                                                     float* __restrict__ out) {
    __shared__ uint32_t Tt[TROWS * TROWSZ];  // 68112 B -> 2 blocks/CU

    const int jt = blockIdx.x;               // 0..32
    const int b  = blockIdx.y;
    const int tid = threadIdx.x, lane = tid & 63, w = tid >> 6;
    const int j0 = jt * 128;
    const float* sb = spec + (size_t)b * NFREQ * NT;

    // ---- stage T[tl][f] bf16, tl = t-(j0-1), tl 0..128; 4-aligned float4 loads ----
    {
        const int fr = lane >> 2;            // 0..15 (f within 16-group)
        const int par = fr & 1;              // f parity
        const int tsub = lane & 3;           // t-chunk sub-index
        for (int u = 0; u < 9; ++u) {
            int tc = tsub + u * 4;           // 0..35, valid <= 32
            bool tcok = (tc <= 32);
            #pragma unroll
            for (int fo = 0; fo < 64; fo += 16) {
                int f = w * 64 + fo + fr;
                int t0 = j0 - 4 + tc * 4;    // 4-aligned; OOB chunks are FULLY oob
                floatx4 v = {0.f, 0.f, 0.f, 0.f};
                if (tcok && t0 >= 0 && t0 <= NT - 4)
                    v = *reinterpret_cast<const floatx4*>(sb + (size_t)f * NT + t0);
                uint32_t h[4], o[4];
                #pragma unroll
                for (int e = 0; e < 4; ++e) h[e] = (f_as_u(v[e]) + 0x8000u) >> 16;
                #pragma unroll
                for (int e = 0; e < 4; ++e) o[e] = (uint32_t)__shfl_xor((int)h[e], 4);
                // even-parity lane packs elems 0,1 (self=low); odd packs 2,3 (self=high)
                uint32_t pk0 = par ? ((o[2] & 0xffffu) | (h[2] << 16))
                                   : ((h[0] & 0xffffu) | (o[0] << 16));
                uint32_t pk1 = par ? ((o[3] & 0xffffu) | (h[3] << 16))
                                   : ((h[1] & 0xffffu) | (o[1] << 16));
                int fp = (w * 64 + fo) / 2 + (fr >> 1);
                int tw0 = tc * 4 - 3 + par * 2;          // tl of pk0
                if (tcok) {
                    if ((unsigned)tw0 <= 128u)       Tt[tw0 * TROWSZ + fp]       = pk0;
                    if ((unsigned)(tw0 + 1) <= 128u) Tt[(tw0 + 1) * TROWSZ + fp] = pk1;
                }
            }
        }
    }
    __syncthreads();                         // the ONLY barrier

    const int row16 = lane & 15, q = lane >> 4;
    floatx4 acc[8][4] = {};
    const uint8_t* Tb = reinterpret_cast<const uint8_t*>(Tt);
    const bf16* kbw = kbF + (size_t)w * 64 * 32;   // wave's n-slice base

    #pragma unroll 2
    for (int kki = 0; kki < 16; ++kki) {
        bf16x8 bfr[4];
        #pragma unroll
        for (int jn = 0; jn < 4; ++jn)
            bfr[jn] = *reinterpret_cast<const bf16x8*>(
                kbw + (size_t)kki * 8192 + (jn * 16 + row16) * 32 + q * 8);
        const uint8_t* Ta = Tb + (size_t)(row16 + (kki >= 8 ? 1 : 0)) * 528
                               + (kki & 7) * 64 + q * 16;
        #pragma unroll
        for (int i = 0; i < 8; ++i) {
            bf16x8 af = *reinterpret_cast<const bf16x8*>(Ta + (size_t)i * 16 * 528);
            #pragma unroll
            for (int jn = 0; jn < 4; ++jn)
                acc[i][jn] = __builtin_amdgcn_mfma_f32_16x16x32_bf16(af, bfr[jn], acc[i][jn], 0, 0, 0);
        }
    }

    // epilogue: C/D layout col=lane&15 (n), row=q*4+e (j within 16)
    #pragma unroll
    for (int i = 0; i < 8; ++i) {
        #pragma unroll
        for (int e = 0; e < 4; ++e) {
            int j = j0 + i * 16 + q * 4 + e;
            if (j <= 4096) {
                float* orow = out + (size_t)b * LOUT + (size_t)j * 256 + w * 64;
                #pragma unroll
                for (int jn = 0; jn < 4; ++jn)
                    orow[jn * 16 + row16] = acc[i][jn][e];
            }
        }
    }
}

extern "C" void kernel_launch(void* const* d_in, const int* in_sizes, int n_in,
                              void* d_out, int out_size, void* d_ws, size_t ws_size,
                              hipStream_t stream) {
    const float* spec = (const float*)d_in[0];   // [16][1][256][4096] fp32
    const float* ker  = (const float*)d_in[1];   // [512][256] fp32
    float* out = (float*)d_out;                  // [16][1048832] fp32

    bf16* kbF = (bf16*)d_ws;                     // 256 KB scratch

    build_kb<<<512, 256, 0, stream>>>(ker, kbF);
    imdct_gemm<<<dim3(33, NB), 256, 0, stream>>>(spec, kbF, out);
}